// Round 3
// baseline (627.231 us; speedup 1.0000x reference)
//
#include <hip/hip_runtime.h>
#include <hip/hip_bf16.h>

typedef __attribute__((ext_vector_type(8))) short short8;   // 8 x bf16
typedef __attribute__((ext_vector_type(4))) float floatx4;  // MFMA acc

__device__ __forceinline__ ushort f2bf(float f) {
    union { __hip_bfloat16 h; ushort u; } cv;
    cv.h = __float2bfloat16(f);
    return cv.u;
}
__device__ __forceinline__ float bflo(unsigned int u) { return __uint_as_float(u << 16); }
__device__ __forceinline__ float bfhi(unsigned int u) { return __uint_as_float(u & 0xffff0000u); }

// ======================= K1: conv GEMM ====================================
// y[b][px][c] (bf16, c contiguous) = x[b][ci][px] . Wc[c][ci] + bc[c]
#define XSTR 72   // ushorts per px row (144 B, 16B-aligned rows)

__global__ __launch_bounds__(256, 2)
void conv_gemm(const float* __restrict__ x, const float* __restrict__ Wc,
               const float* __restrict__ bc, ushort* __restrict__ y) {
    __shared__ ushort xs[128 * XSTR];   // 18,432 B
    const int tid = threadIdx.x, lane = tid & 63, wv = tid >> 6;
    const int b = blockIdx.y;
    const int px0 = blockIdx.x * 128;

    // ---- stage x tile [128 px][64 ci] -> LDS bf16 (coalesced 256B loads) ----
    {
        const int pxl = tid & 127;
        const int c0 = (tid >> 7) * 32;
        const float* xp = x + (((size_t)(b * 64 + c0)) << 14) + px0 + pxl;
        ushort* dst = xs + pxl * XSTR + c0;
        #pragma unroll
        for (int k = 0; k < 32; k += 2) {
            unsigned int u = (unsigned int)f2bf(xp[(size_t)k << 14])
                           | ((unsigned int)f2bf(xp[(size_t)(k + 1) << 14]) << 16);
            *(unsigned int*)(dst + k) = u;
        }
    }

    // ---- A-operand: W fragments (m = c_out) --------------------------------
    const int col = lane & 15, kq = lane >> 4;
    short8 aw[8][2];
    #pragma unroll
    for (int t = 0; t < 8; ++t) {
        #pragma unroll
        for (int h = 0; h < 2; ++h) {
            const float* wp = Wc + (t * 16 + col) * 64 + h * 32 + kq * 8;
            float4 wa = *(const float4*)wp;
            float4 wb = *(const float4*)(wp + 4);
            short8 f;
            f[0] = (short)f2bf(wa.x); f[1] = (short)f2bf(wa.y);
            f[2] = (short)f2bf(wa.z); f[3] = (short)f2bf(wa.w);
            f[4] = (short)f2bf(wb.x); f[5] = (short)f2bf(wb.y);
            f[6] = (short)f2bf(wb.z); f[7] = (short)f2bf(wb.w);
            aw[t][h] = f;
        }
    }
    __syncthreads();

    // ---- B-operand: X fragments (n = px), 2 n-tiles per wave ---------------
    short8 bx[2][2];
    #pragma unroll
    for (int nt = 0; nt < 2; ++nt) {
        const ushort* bp = xs + (wv * 32 + nt * 16 + col) * XSTR + kq * 8;
        bx[nt][0] = *(const short8*)bp;
        bx[nt][1] = *(const short8*)(bp + 32);
    }

    floatx4 acc[2][8];
    #pragma unroll
    for (int nt = 0; nt < 2; ++nt)
        #pragma unroll
        for (int t = 0; t < 8; ++t) acc[nt][t] = (floatx4){0.f, 0.f, 0.f, 0.f};

    #pragma unroll
    for (int t = 0; t < 8; ++t) {
        #pragma unroll
        for (int nt = 0; nt < 2; ++nt) {
            acc[nt][t] = __builtin_amdgcn_mfma_f32_16x16x32_bf16(aw[t][0], bx[nt][0], acc[nt][t], 0, 0, 0);
            acc[nt][t] = __builtin_amdgcn_mfma_f32_16x16x32_bf16(aw[t][1], bx[nt][1], acc[nt][t], 0, 0, 0);
        }
    }

    // ---- epilogue: D col = px, row = c_out -> dwordx2 stores ---------------
    #pragma unroll
    for (int nt = 0; nt < 2; ++nt) {
        const int px = px0 + wv * 32 + nt * 16 + col;
        ushort* yp = y + ((size_t)b * 16384 + px) * 128;
        #pragma unroll
        for (int t = 0; t < 8; ++t) {
            float4 bias = *(const float4*)(bc + t * 16 + kq * 4);
            float v0 = acc[nt][t][0] + bias.x;
            float v1 = acc[nt][t][1] + bias.y;
            float v2 = acc[nt][t][2] + bias.z;
            float v3 = acc[nt][t][3] + bias.w;
            uint2 u;
            u.x = (unsigned int)f2bf(v0) | ((unsigned int)f2bf(v1) << 16);
            u.y = (unsigned int)f2bf(v2) | ((unsigned int)f2bf(v3) << 16);
            *(uint2*)(yp + t * 16 + kq * 4) = u;
        }
    }
}

// ======================= K2: 3x3 local attention ==========================
// one lane = one output pixel; y rows gathered via L1/L2; no LDS/barriers
__global__ __launch_bounds__(256, 4)
void attn_local(const ushort* __restrict__ y, float* __restrict__ out) {
    const int tid = threadIdx.x, lane = tid & 63, wv = tid >> 6;
    const int gid = blockIdx.x * 4 + wv;        // 0..2047 strips
    const int b = gid >> 8;
    const int rem = gid & 255;
    const int h = rem >> 1;
    const int w = (rem & 1) * 64 + lane;

    const ushort* yb = y + ((size_t)b << 14) * 128;

    const ushort* pn[9];
    float valid[9];
    #pragma unroll
    for (int n = 0; n < 9; ++n) {
        const int dy = n / 3 - 1, dx = n % 3 - 1;
        const int hn = h + dy, wn = w + dx;
        const bool v = (hn >= 0 && hn < 128 && wn >= 0 && wn < 128);
        const int hc = min(127, max(0, hn));
        const int wc = min(127, max(0, wn));
        pn[n] = yb + ((size_t)(hc << 7) + wc) * 128;
        valid[n] = v ? 1.f : 0.f;
    }

    // ---- pass 1: scores ----------------------------------------------------
    float s[9];
    #pragma unroll
    for (int n = 0; n < 9; ++n) s[n] = 0.f;

    #pragma unroll
    for (int k = 0; k < 16; ++k) {
        uint4 p[9];
        #pragma unroll
        for (int n = 0; n < 9; ++n) p[n] = *(const uint4*)(pn[n] + k * 8);
        float cf[8];
        cf[0] = bflo(p[4].x); cf[1] = bfhi(p[4].x);
        cf[2] = bflo(p[4].y); cf[3] = bfhi(p[4].y);
        cf[4] = bflo(p[4].z); cf[5] = bfhi(p[4].z);
        cf[6] = bflo(p[4].w); cf[7] = bfhi(p[4].w);
        #pragma unroll
        for (int n = 0; n < 9; ++n) {
            s[n] += bflo(p[n].x) * cf[0] + bfhi(p[n].x) * cf[1]
                  + bflo(p[n].y) * cf[2] + bfhi(p[n].y) * cf[3]
                  + bflo(p[n].z) * cf[4] + bfhi(p[n].z) * cf[5]
                  + bflo(p[n].w) * cf[6] + bfhi(p[n].w) * cf[7];
        }
    }

    // ---- softmax (lane-private) -------------------------------------------
    const float scale = 0.08838834764831845f;   // 1/sqrt(128)
    #pragma unroll
    for (int n = 0; n < 9; ++n) s[n] = valid[n] * s[n] * scale;
    float m = s[0];
    #pragma unroll
    for (int n = 1; n < 9; ++n) m = fmaxf(m, s[n]);
    float a[9], sum = 0.f;
    #pragma unroll
    for (int n = 0; n < 9; ++n) { a[n] = __expf(s[n] - m); sum += a[n]; }
    const float inv = 1.f / sum;
    #pragma unroll
    for (int n = 0; n < 9; ++n) a[n] = valid[n] * a[n] * inv;

    // ---- pass 2: weighted sum + coalesced stores --------------------------
    float* ob = out + (((size_t)b * 128) * 128 + h) * 128 + w;
    #pragma unroll
    for (int k = 0; k < 16; ++k) {
        float o[8];
        #pragma unroll
        for (int j = 0; j < 8; ++j) o[j] = 0.f;
        #pragma unroll
        for (int n = 0; n < 9; ++n) {
            uint4 p = *(const uint4*)(pn[n] + k * 8);
            const float an = a[n];
            o[0] += an * bflo(p.x); o[1] += an * bfhi(p.x);
            o[2] += an * bflo(p.y); o[3] += an * bfhi(p.y);
            o[4] += an * bflo(p.z); o[5] += an * bfhi(p.z);
            o[6] += an * bflo(p.w); o[7] += an * bfhi(p.w);
        }
        #pragma unroll
        for (int j = 0; j < 8; ++j)
            ob[(size_t)(k * 8 + j) * 16384] = o[j];
    }
}

extern "C" void kernel_launch(void* const* d_in, const int* in_sizes, int n_in,
                              void* d_out, int out_size, void* d_ws, size_t ws_size,
                              hipStream_t stream) {
    const float* x  = (const float*)d_in[0];
    const float* Wc = (const float*)d_in[1];
    const float* bc = (const float*)d_in[2];
    float* out = (float*)d_out;
    ushort* y = (ushort*)d_ws;   // 8*16384*128 bf16 = 33.55 MB

    conv_gemm<<<dim3(128, 8), dim3(256), 0, stream>>>(x, Wc, bc, y);
    attn_local<<<dim3(512), dim3(256), 0, stream>>>(y, out);
}

// Round 4
// 161.447 us; speedup vs baseline: 3.8851x; 3.8851x over previous
//
#include <hip/hip_runtime.h>
#include <hip/hip_bf16.h>

typedef __attribute__((ext_vector_type(8))) short short8;   // 8 x bf16
typedef __attribute__((ext_vector_type(4))) float floatx4;  // MFMA acc

__device__ __forceinline__ ushort f2bf(float f) {
    union { __hip_bfloat16 h; ushort u; } cv;
    cv.h = __float2bfloat16(f);
    return cv.u;
}
__device__ __forceinline__ float bflo(unsigned int u) { return __uint_as_float(u << 16); }
__device__ __forceinline__ float bfhi(unsigned int u) { return __uint_as_float(u & 0xffff0000u); }

__device__ __forceinline__ float dot8(uint4 p, const float* cf) {
    return bflo(p.x)*cf[0] + bfhi(p.x)*cf[1] + bflo(p.y)*cf[2] + bfhi(p.y)*cf[3]
         + bflo(p.z)*cf[4] + bfhi(p.z)*cf[5] + bflo(p.w)*cf[6] + bfhi(p.w)*cf[7];
}
__device__ __forceinline__ void unpack8(uint4 p, float* cf) {
    cf[0] = bflo(p.x); cf[1] = bfhi(p.x); cf[2] = bflo(p.y); cf[3] = bfhi(p.y);
    cf[4] = bflo(p.z); cf[5] = bfhi(p.z); cf[6] = bflo(p.w); cf[7] = bfhi(p.w);
}
__device__ __forceinline__ void fma8(uint4 p, float a, float* o) {
    o[0] += a*bflo(p.x); o[1] += a*bfhi(p.x); o[2] += a*bflo(p.y); o[3] += a*bfhi(p.y);
    o[4] += a*bflo(p.z); o[5] += a*bfhi(p.z); o[6] += a*bflo(p.w); o[7] += a*bfhi(p.w);
}

// ======================= K1: conv GEMM ====================================
// y[b][px][c] (bf16) = x[b][ci][px] . Wc[c][ci] + bc[c]
// xs: [128 px][72 ush], 8-ush chunks xor-swizzled by (px&7)
// ystage (reuses sm): [128 px][128 ush], 8-ush chunks xor-swizzled by (px&7)
__global__ __launch_bounds__(256, 4)
void conv_gemm(const float* __restrict__ x, const float* __restrict__ Wc,
               const float* __restrict__ bc, ushort* __restrict__ y) {
    __shared__ __align__(16) ushort sm[128 * 128];   // 32 KB
    const int tid = threadIdx.x, lane = tid & 63, wv = tid >> 6;
    const int b = blockIdx.y;
    const int px0 = blockIdx.x * 128;                // one image row per block

    // ---- stage x tile [128 px][64 ci] -> xs (coalesced 512B per k) ---------
    {
        const int pxl = tid & 127, c0 = (tid >> 7) * 32, sw = pxl & 7;
        const float* xp = x + (((size_t)(b * 64 + c0)) << 14) + px0 + pxl;
        ushort* row = sm + pxl * 72;
        #pragma unroll
        for (int k = 0; k < 32; k += 2) {
            int cush = c0 + k;
            unsigned int u = (unsigned int)f2bf(xp[(size_t)k << 14])
                           | ((unsigned int)f2bf(xp[(size_t)(k + 1) << 14]) << 16);
            *(unsigned int*)(row + (((cush >> 3) ^ sw) << 3) + (cush & 7)) = u;
        }
    }

    // ---- A-operand: W fragments (m = c_out) --------------------------------
    const int col = lane & 15, kq = lane >> 4;
    short8 aw[8][2];
    #pragma unroll
    for (int t = 0; t < 8; ++t) {
        #pragma unroll
        for (int h = 0; h < 2; ++h) {
            const float* wp = Wc + (t * 16 + col) * 64 + h * 32 + kq * 8;
            float4 wa = *(const float4*)wp;
            float4 wb = *(const float4*)(wp + 4);
            short8 f;
            f[0] = (short)f2bf(wa.x); f[1] = (short)f2bf(wa.y);
            f[2] = (short)f2bf(wa.z); f[3] = (short)f2bf(wa.w);
            f[4] = (short)f2bf(wb.x); f[5] = (short)f2bf(wb.y);
            f[6] = (short)f2bf(wb.z); f[7] = (short)f2bf(wb.w);
            aw[t][h] = f;
        }
    }
    __syncthreads();

    // ---- B-operand: X fragments (n = px), 2 n-tiles per wave ---------------
    short8 bx[2][2];
    #pragma unroll
    for (int nt = 0; nt < 2; ++nt) {
        const int pxl = wv * 32 + nt * 16 + col, s = pxl & 7;
        const ushort* bp = sm + pxl * 72;
        bx[nt][0] = *(const short8*)(bp + ((kq ^ s) << 3));
        bx[nt][1] = *(const short8*)(bp + (((kq + 4) ^ s) << 3));
    }
    __syncthreads();   // xs dead -> sm becomes ystage

    floatx4 acc[2][8];
    #pragma unroll
    for (int nt = 0; nt < 2; ++nt)
        #pragma unroll
        for (int t = 0; t < 8; ++t) acc[nt][t] = (floatx4){0.f, 0.f, 0.f, 0.f};
    #pragma unroll
    for (int t = 0; t < 8; ++t) {
        #pragma unroll
        for (int nt = 0; nt < 2; ++nt) {
            acc[nt][t] = __builtin_amdgcn_mfma_f32_16x16x32_bf16(aw[t][0], bx[nt][0], acc[nt][t], 0, 0, 0);
            acc[nt][t] = __builtin_amdgcn_mfma_f32_16x16x32_bf16(aw[t][1], bx[nt][1], acc[nt][t], 0, 0, 0);
        }
    }

    // ---- D (col=px, row=c) -> ystage (bf16, swizzled) ----------------------
    #pragma unroll
    for (int nt = 0; nt < 2; ++nt) {
        const int pxl = wv * 32 + nt * 16 + col, s = pxl & 7;
        ushort* prow = sm + pxl * 128;
        #pragma unroll
        for (int t = 0; t < 8; ++t) {
            float4 bias = *(const float4*)(bc + t * 16 + kq * 4);
            float v0 = acc[nt][t][0] + bias.x;
            float v1 = acc[nt][t][1] + bias.y;
            float v2 = acc[nt][t][2] + bias.z;
            float v3 = acc[nt][t][3] + bias.w;
            uint2 u;
            u.x = (unsigned int)f2bf(v0) | ((unsigned int)f2bf(v1) << 16);
            u.y = (unsigned int)f2bf(v2) | ((unsigned int)f2bf(v3) << 16);
            const int chunk = t * 2 + (kq >> 1), off = (kq & 1) * 4;
            *(uint2*)(prow + ((chunk ^ s) << 3) + off) = u;
        }
    }
    __syncthreads();

    // ---- cooperative y store: 1KB contiguous per wave-inst ------------------
    #pragma unroll
    for (int r = 0; r < 8; ++r) {
        const int pxr = r * 16 + (tid >> 4), seg = tid & 15, s = pxr & 7;
        uint4 v = *(const uint4*)(sm + pxr * 128 + ((seg ^ s) << 3));
        *(uint4*)(y + ((size_t)b * 16384 + px0 + pxr) * 128 + seg * 8) = v;
    }
}

// ======================= K2: 3x3 local attention ==========================
// block = 32w x 4h out-tile; stages 6x34 y-halo region once in LDS (swizzled);
// 2 threads/px (64 ch each), shfl_xor(32) score reduce; full-line f32 stores.
__global__ __launch_bounds__(256, 4)
void attn_local(const ushort* __restrict__ y, float* __restrict__ out) {
    __shared__ __align__(16) ushort ts[204 * 128];   // 52,224 B -> 3 blocks/CU
    const int tid = threadIdx.x, lane = tid & 63, wv = tid >> 6;
    const int b = blockIdx.z, h0 = blockIdx.y * 4, w0 = blockIdx.x * 32;
    const ushort* yb = y + (((size_t)b) << 14) * 128;

    // ---- stage region [6 rows][34 cols][128 c], zero-pad outside image ------
    #pragma unroll
    for (int it = 0; it < 13; ++it) {
        int idx = it * 256 + tid;
        if (idx < 3264) {
            int px = idx >> 4, seg = idx & 15;
            int rr = (px * 965) >> 15;               // px / 34
            int cc = px - rr * 34;
            int gh = h0 - 1 + rr, gw = w0 - 1 + cc;
            uint4 v = make_uint4(0u, 0u, 0u, 0u);
            if (gh >= 0 && gh < 128 && gw >= 0 && gw < 128)
                v = *(const uint4*)(yb + ((size_t)(gh * 128 + gw)) * 128 + seg * 8);
            *(uint4*)(ts + px * 128 + ((seg ^ (px & 7)) << 3)) = v;
        }
    }
    __syncthreads();

    const int ox = lane & 31, half = lane >> 5, oy = wv;
    const int pc = (oy + 1) * 34 + ox + 1;
    const int sc = pc & 7;
    const ushort* cb = ts + pc * 128;

    // ---- pass 1: scores (this thread covers channels half*64 .. +63) -------
    float s9[9];
    #pragma unroll
    for (int n = 0; n < 9; ++n) s9[n] = 0.f;
    #pragma unroll
    for (int kb = 0; kb < 4; ++kb) {
        const int ch0 = half * 8 + kb * 2;
        uint4 c0 = *(const uint4*)(cb + ((ch0 ^ sc) << 3));
        uint4 c1 = *(const uint4*)(cb + (((ch0 + 1) ^ sc) << 3));
        float cf[16];
        unpack8(c0, cf); unpack8(c1, cf + 8);
        #pragma unroll
        for (int n = 0; n < 9; ++n) {
            const int pn = pc + (n / 3 - 1) * 34 + (n % 3 - 1);
            const int sn = pn & 7;
            const ushort* nb = ts + pn * 128;
            uint4 u0 = *(const uint4*)(nb + ((ch0 ^ sn) << 3));
            uint4 u1 = *(const uint4*)(nb + (((ch0 + 1) ^ sn) << 3));
            s9[n] += dot8(u0, cf) + dot8(u1, cf + 8);
        }
    }

    // ---- softmax (halves reduced via shfl, then redundant) ------------------
    const float scale = 0.08838834764831845f;        // 1/sqrt(128)
    #pragma unroll
    for (int n = 0; n < 9; ++n) {
        s9[n] += __shfl_xor(s9[n], 32);
        s9[n] *= scale;
    }
    float m = s9[0];
    #pragma unroll
    for (int n = 1; n < 9; ++n) m = fmaxf(m, s9[n]);
    float sum = 0.f;
    #pragma unroll
    for (int n = 0; n < 9; ++n) { s9[n] = __expf(s9[n] - m); sum += s9[n]; }
    const float inv = 1.f / sum;
    #pragma unroll
    for (int n = 0; n < 9; ++n) s9[n] *= inv;

    // ---- pass 2: weighted sum, full-line stores -----------------------------
    #pragma unroll
    for (int kb = 0; kb < 4; ++kb) {
        const int ch0 = half * 8 + kb * 2;
        float o[16];
        #pragma unroll
        for (int j = 0; j < 16; ++j) o[j] = 0.f;
        #pragma unroll
        for (int n = 0; n < 9; ++n) {
            const int pn = pc + (n / 3 - 1) * 34 + (n % 3 - 1);
            const int sn = pn & 7;
            const ushort* nb = ts + pn * 128;
            uint4 u0 = *(const uint4*)(nb + ((ch0 ^ sn) << 3));
            uint4 u1 = *(const uint4*)(nb + (((ch0 + 1) ^ sn) << 3));
            fma8(u0, s9[n], o);
            fma8(u1, s9[n], o + 8);
        }
        const int cbase = half * 64 + kb * 16;
        float* op = out + (((size_t)(b * 128 + cbase) * 128) + h0 + oy) * 128 + w0 + ox;
        #pragma unroll
        for (int j = 0; j < 16; ++j)
            op[(size_t)j * 16384] = o[j];
    }
}

extern "C" void kernel_launch(void* const* d_in, const int* in_sizes, int n_in,
                              void* d_out, int out_size, void* d_ws, size_t ws_size,
                              hipStream_t stream) {
    const float* x  = (const float*)d_in[0];
    const float* Wc = (const float*)d_in[1];
    const float* bc = (const float*)d_in[2];
    float* out = (float*)d_out;
    ushort* y = (ushort*)d_ws;   // 8*16384*128 bf16 = 33.55 MB

    conv_gemm<<<dim3(128, 8), dim3(256), 0, stream>>>(x, Wc, bc, y);
    attn_local<<<dim3(4, 32, 8), dim3(256), 0, stream>>>(y, out);
}